// Round 5
// baseline (914.530 us; speedup 1.0000x reference)
//
#include <hip/hip_runtime.h>
#include <math.h>

#define HIDDEN  512
#define INPUT   8
#define NUM_MIX 2
#define BATCH   64
#define SEQ     2048
#define DD      12
#define KOUT    10
#define TTILE   16
#define NTILES  (SEQ/TTILE)

// h-state kept pre-scaled by 2*log2(e): tanh(h) = 1 - 2*rcp(exp2(h_s)+1)
#define SCALE_F 2.8853900817779268
#define AB_F    0.09765625f   /* alpha*BASE_SCALE/HIDDEN = 50/512 */

typedef float v2f __attribute__((ext_vector_type(2)));
typedef float f4v __attribute__((ext_vector_type(4)));

__device__ __forceinline__ v2f pk_fma(v2f a, v2f b, v2f c) {
    return __builtin_elementwise_fma(a, b, c);
}

template<int CTRL>
__device__ __forceinline__ float dpp_add(float x) {
    int y = __builtin_amdgcn_update_dpp(0, __float_as_int(x), CTRL, 0xF, 0xF, true);
    return x + __int_as_float(y);
}
__device__ __forceinline__ float wave_allsum(float x) {
    x = dpp_add<0x111>(x);   // row_shr:1
    x = dpp_add<0x112>(x);   // row_shr:2
    x = dpp_add<0x114>(x);   // row_shr:4
    x = dpp_add<0x118>(x);   // row_shr:8
    x = dpp_add<0x142>(x);   // row_bcast:15
    x = dpp_add<0x143>(x);   // row_bcast:31
    return __int_as_float(__builtin_amdgcn_readlane(__float_as_int(x), 63));
}

__global__ __launch_bounds__(256) void fsm_rnn_kernel(
    const float* __restrict__ x,          // (B, SEQ, INPUT)
    const float* __restrict__ means,      // (NUM_MIX, DD)
    const float* __restrict__ scale_tril, // (NUM_MIX, DD, DD)
    const float* __restrict__ mixw,       // (NUM_MIX,)
    const float* __restrict__ seeds,      // (4, HIDDEN, DD)
    const int*   __restrict__ cur_seeds,  // (B,)
    float*       __restrict__ out)        // (B, SEQ, KOUT)
{
    // Setup-only arrays overlay the main-loop IxB (128KB) in a union.
    __shared__ union {
        struct {
            float IvL[2][HIDDEN][INPUT];   // 32KB scaled alpha*I per batch
            float PM[2][4][HIDDEN];        // 16KB PM0,PM1,N0,N1 per batch
        } s;
        float IxB[2][2][TTILE][HIDDEN];    // [batch][dbuf][tt][h]  128KB
    } u;
    __shared__ __align__(16) float xsB[2][2][TTILE*INPUT]; // [batch][dbuf] 2KB
    __shared__ __align__(8)  float vring[2][2][TTILE][2];  // [batch][dbuf] 1KB
    __shared__ double Leff[DD*DD];
    __shared__ double meansw[DD];

    const int tid  = threadIdx.x;
    const int lane = tid & 63;
    const int wid  = tid >> 6;
    const int g    = blockIdx.x;             // batch pair
    const float* xb[2]   = { x   + (size_t)(2*g  )*SEQ*INPUT,
                             x   + (size_t)(2*g+1)*SEQ*INPUT };
    float*       outb[2] = { out + (size_t)(2*g  )*SEQ*KOUT,
                             out + (size_t)(2*g+1)*SEQ*KOUT };
    const int sd[2] = { cur_seeds[2*g], cur_seeds[2*g+1] };

    // ---- mixture weights ----
    double w0 = fmax((double)mixw[0], 1e-6);
    double w1 = fmax((double)mixw[1], 1e-6);
    double wsum = w0 + w1; w0 /= wsum; w1 /= wsum;

    // ---- weighted clamped-tril L, weighted means (batch-independent) ----
    if (tid < DD*DD) {
        int d = tid / DD, e = tid % DD;
        double acc = 0.0;
        #pragma unroll
        for (int i = 0; i < NUM_MIX; ++i) {
            float v = scale_tril[i*DD*DD + d*DD + e];
            float c = (d > e) ? v : (d == e ? fabsf(v - 1e-12f) + 1e-12f : 0.0f);
            acc += (i == 0 ? w0 : w1) * (double)c;
        }
        Leff[tid] = acc;
    }
    if (tid < DD)
        meansw[tid] = w0 * (double)means[tid] + w1 * (double)means[DD + tid];
    // stage x tiles 0,1 for both batches (2*TTILE*INPUT = 256 floats each)
    ((float*)xsB)[tid]       = xb[0][tid];
    ((float*)xsB)[256 + tid] = xb[1][tid];
    __syncthreads();

    // ---- per-h params (double), both batches, stored pre-scaled ----
    #pragma unroll
    for (int bi = 0; bi < 2; ++bi) {
        #pragma unroll
        for (int rr = 0; rr < 2; ++rr) {
            int h = tid + rr*256;
            const float* sh = &seeds[(sd[bi]*HIDDEN + h)*DD];
            double comb[DD];
            #pragma unroll
            for (int d = 0; d < DD; ++d) {
                double acc = meansw[d];
                for (int e = 0; e <= d; ++e)
                    acc += Leff[d*DD + e] * (double)sh[e];
                comb[d] = acc;
            }
            u.s.PM[bi][0][h] = (float)(SCALE_F * (double)AB_F * comb[0]);
            u.s.PM[bi][1][h] = (float)(SCALE_F * (double)AB_F * comb[1]);
            u.s.PM[bi][2][h] = (float)comb[2];
            u.s.PM[bi][3][h] = (float)comb[3];
            #pragma unroll
            for (int i = 0; i < INPUT; ++i)
                u.s.IvL[bi][h][i] = (float)(SCALE_F * 0.1 * comb[4 + i]);
        }
    }
    __syncthreads();

    // ---- per-role register state ----
    v2f AM0[2][4], AM1[2][4], NN0[2][4], NN1[2][4], H[2][4];
    f4v IvA[2][3], IvC[2][3];
    float zf = 0.0f, wst = 0.0f;
    const int pid = (wid - 1)*64 + lane;   // producer id 0..191
    const int zi  = lane - 56;

    if (wid == 0) {
        // consumer owns h = lane + 64*j for both batches
        #pragma unroll
        for (int bi = 0; bi < 2; ++bi) {
            #pragma unroll
            for (int q = 0; q < 4; ++q) {
                int ha = lane + 64*(2*q), hb = lane + 64*(2*q + 1);
                AM0[bi][q] = (v2f){u.s.PM[bi][0][ha], u.s.PM[bi][0][hb]};
                AM1[bi][q] = (v2f){u.s.PM[bi][1][ha], u.s.PM[bi][1][hb]};
                NN0[bi][q] = (v2f){u.s.PM[bi][2][ha], u.s.PM[bi][2][hb]};
                NN1[bi][q] = (v2f){u.s.PM[bi][3][ha], u.s.PM[bi][3][hb]};
                H[bi][q]   = (v2f){0.0f, 0.0f};
            }
        }
    } else {
        #pragma unroll
        for (int bi = 0; bi < 2; ++bi) {
            #pragma unroll
            for (int q = 0; q < 3; ++q) {
                int h = pid + 192*q;
                if (h < HIDDEN) {
                    IvA[bi][q] = *(const f4v*)&u.s.IvL[bi][h][0];
                    IvC[bi][q] = *(const f4v*)&u.s.IvL[bi][h][4];
                }
            }
        }
    }
    __syncthreads();   // all union reads done before IxB writes clobber

    // producer: fill IxB tile tg (both batches); z-filter on waves 1 (b0) / 2 (b1)
    auto produce = [&](int tg) {
        const int pb = tg & 1;
        #pragma unroll
        for (int bi = 0; bi < 2; ++bi) {
            const float* xs = xsB[bi][pb];
            for (int tt = 0; tt < TTILE; ++tt) {
                f4v xa = *(const f4v*)&xs[tt*INPUT];
                f4v xc = *(const f4v*)&xs[tt*INPUT + 4];
                #pragma unroll
                for (int q = 0; q < 3; ++q) {
                    int h = pid + 192*q;
                    if (h < HIDDEN) {
                        float v =      IvA[bi][q].x * xa.x;
                        v = fmaf(IvA[bi][q].y, xa.y, v);
                        v = fmaf(IvA[bi][q].z, xa.z, v);
                        v = fmaf(IvA[bi][q].w, xa.w, v);
                        v = fmaf(IvC[bi][q].x, xc.x, v);
                        v = fmaf(IvC[bi][q].y, xc.y, v);
                        v = fmaf(IvC[bi][q].z, xc.z, v);
                        v = fmaf(IvC[bi][q].w, xc.w, v);
                        u.IxB[bi][pb][tt][h] = v;
                    }
                }
            }
        }
        if ((wid == 1 || wid == 2) && lane >= 56) {
            const int bi = wid - 1;
            const float* xs = xsB[bi][pb];
            #pragma unroll 4
            for (int tt = 0; tt < TTILE; ++tt) {
                zf = fmaf(0.9f, zf, 0.1f * xs[tt*INPUT + zi]);
                outb[bi][(tg*TTILE + tt)*KOUT + 2 + zi] = zf;
            }
        }
    };

    // w-EMA (cols 0,1): wave1 lanes 54,55 -> batch0; wave2 -> batch1
    auto process_w = [&](int tile) {
        if ((wid == 1 || wid == 2) && (lane == 54 || lane == 55)) {
            const int bi = wid - 1, widx = lane & 1;
            for (int tt = 0; tt < TTILE; ++tt) {
                wst = fmaf(0.9f, wst, AB_F * vring[bi][tile & 1][tt][widx]);
                outb[bi][(tile*TTILE + tt)*KOUT + widx] = wst;
            }
        }
    };

    if (wid != 0) produce(0);
    __syncthreads();

    for (int T = 0; T < NTILES; ++T) {
        if (wid == 0) {
            const int pb = T & 1;
            float cc[2][8], cn[2][8];
            #pragma unroll
            for (int j = 0; j < 8; ++j) {
                cc[0][j] = u.IxB[0][pb][0][lane + 64*j];
                cc[1][j] = u.IxB[1][pb][0][lane + 64*j];
            }
            #pragma unroll
            for (int tt = 0; tt < TTILE; ++tt) {
                if (tt < TTILE-1) {           // conflict-free prefetch of next step
                    #pragma unroll
                    for (int j = 0; j < 8; ++j) {
                        cn[0][j] = u.IxB[0][pb][tt+1][lane + 64*j];
                        cn[1][j] = u.IxB[1][pb][tt+1][lane + 64*j];
                    }
                }
                // tanh for both chains (independent -> co-scheduled)
                v2f TH[2][4];
                #pragma unroll
                for (int bi = 0; bi < 2; ++bi) {
                    #pragma unroll
                    for (int q = 0; q < 4; ++q) {
                        v2f E;
                        E.x = __builtin_amdgcn_exp2f(H[bi][q].x);
                        E.y = __builtin_amdgcn_exp2f(H[bi][q].y);
                        v2f A = E + 1.0f;
                        v2f R;
                        R.x = __builtin_amdgcn_rcpf(A.x);
                        R.y = __builtin_amdgcn_rcpf(A.y);
                        const v2f m2 = {-2.0f, -2.0f}, one = {1.0f, 1.0f};
                        TH[bi][q] = pk_fma(m2, R, one);
                    }
                }
                float p0[2], p1[2];
                #pragma unroll
                for (int bi = 0; bi < 2; ++bi) {
                    v2f s0 = TH[bi][0]*NN0[bi][0];
                    s0 = pk_fma(TH[bi][1], NN0[bi][1], s0);
                    s0 = pk_fma(TH[bi][2], NN0[bi][2], s0);
                    s0 = pk_fma(TH[bi][3], NN0[bi][3], s0);
                    v2f s1 = TH[bi][0]*NN1[bi][0];
                    s1 = pk_fma(TH[bi][1], NN1[bi][1], s1);
                    s1 = pk_fma(TH[bi][2], NN1[bi][2], s1);
                    s1 = pk_fma(TH[bi][3], NN1[bi][3], s1);
                    p0[bi] = s0.x + s0.y;
                    p1[bi] = s1.x + s1.y;
                }
                // 4 independent 6-level DPP chains -> interleaved by scheduler
                float v0A = wave_allsum(p0[0]);
                float v1A = wave_allsum(p1[0]);
                float v0B = wave_allsum(p0[1]);
                float v1B = wave_allsum(p1[1]);

                const v2f nine = {0.9f, 0.9f};
                float v0s[2] = {v0A, v0B}, v1s[2] = {v1A, v1B};
                #pragma unroll
                for (int bi = 0; bi < 2; ++bi) {
                    v2f hc0 = pk_fma(nine, H[bi][0], (v2f){cc[bi][0], cc[bi][1]});
                    v2f hc1 = pk_fma(nine, H[bi][1], (v2f){cc[bi][2], cc[bi][3]});
                    v2f hc2 = pk_fma(nine, H[bi][2], (v2f){cc[bi][4], cc[bi][5]});
                    v2f hc3 = pk_fma(nine, H[bi][3], (v2f){cc[bi][6], cc[bi][7]});
                    v2f v0v = {v0s[bi], v0s[bi]}, v1v = {v1s[bi], v1s[bi]};
                    H[bi][0] = pk_fma(AM0[bi][0], v0v, pk_fma(AM1[bi][0], v1v, hc0));
                    H[bi][1] = pk_fma(AM0[bi][1], v0v, pk_fma(AM1[bi][1], v1v, hc1));
                    H[bi][2] = pk_fma(AM0[bi][2], v0v, pk_fma(AM1[bi][2], v1v, hc2));
                    H[bi][3] = pk_fma(AM0[bi][3], v0v, pk_fma(AM1[bi][3], v1v, hc3));
                }
                if (lane == 0) {
                    *(v2f*)&vring[0][pb][tt][0] = (v2f){v0A, v1A};
                    *(v2f*)&vring[1][pb][tt][0] = (v2f){v0B, v1B};
                }
                #pragma unroll
                for (int j = 0; j < 8; ++j) {
                    cc[0][j] = cn[0][j];
                    cc[1][j] = cn[1][j];
                }
            }
        } else {
            if (T + 1 < NTILES) produce(T + 1);
            if (wid == 3 && T + 2 < NTILES) {      // stage x tile T+2, both batches
                const int base = (T + 2)*(TTILE*INPUT);
                #pragma unroll
                for (int bi = 0; bi < 2; ++bi) {
                    xsB[bi][T & 1][lane]      = xb[bi][base + lane];
                    xsB[bi][T & 1][lane + 64] = xb[bi][base + lane + 64];
                }
            }
            if (T >= 1) process_w(T - 1);
        }
        __syncthreads();
    }
    process_w(NTILES - 1);
}

extern "C" void kernel_launch(void* const* d_in, const int* in_sizes, int n_in,
                              void* d_out, int out_size, void* d_ws, size_t ws_size,
                              hipStream_t stream) {
    (void)d_ws; (void)ws_size;
    const float* x          = (const float*)d_in[0];
    const float* means      = (const float*)d_in[1];
    const float* scale_tril = (const float*)d_in[2];
    const float* mixw       = (const float*)d_in[3];
    const float* seeds      = (const float*)d_in[4];
    const int*   cur_seeds  = (const int*)d_in[5];
    float* out = (float*)d_out;

    fsm_rnn_kernel<<<BATCH/2, 256, 0, stream>>>(
        x, means, scale_tril, mixw, seeds, cur_seeds, out);
}

// Round 6
// 532.948 us; speedup vs baseline: 1.7160x; 1.7160x over previous
//
#include <hip/hip_runtime.h>
#include <math.h>

#define HIDDEN  512
#define INPUT   8
#define NUM_MIX 2
#define BATCH   64
#define SEQ     2048
#define DD      12
#define KOUT    10
#define TTILE   16
#define NTILES  (SEQ/TTILE)

// h-state kept pre-scaled by 2*log2(e): tanh(h) = 1 - 2*rcp(exp2(h_s)+1)
#define SCALE_F 2.8853900817779268
#define AB_F    0.09765625f   /* alpha*BASE_SCALE/HIDDEN = 50/512 */

typedef float v2f __attribute__((ext_vector_type(2)));
typedef float f4v __attribute__((ext_vector_type(4)));

__device__ __forceinline__ v2f pk_fma(v2f a, v2f b, v2f c) {
    return __builtin_elementwise_fma(a, b, c);
}

template<int CTRL>
__device__ __forceinline__ float dpp_add(float x) {
    int y = __builtin_amdgcn_update_dpp(0, __float_as_int(x), CTRL, 0xF, 0xF, true);
    return x + __int_as_float(y);
}
__device__ __forceinline__ float wave_allsum(float x) {
    x = dpp_add<0x111>(x);   // row_shr:1
    x = dpp_add<0x112>(x);   // row_shr:2
    x = dpp_add<0x114>(x);   // row_shr:4
    x = dpp_add<0x118>(x);   // row_shr:8
    x = dpp_add<0x142>(x);   // row_bcast:15
    x = dpp_add<0x143>(x);   // row_bcast:31
    return __int_as_float(__builtin_amdgcn_readlane(__float_as_int(x), 63));
}

__global__ __launch_bounds__(256) void fsm_rnn_kernel(
    const float* __restrict__ x,          // (B, SEQ, INPUT)
    const float* __restrict__ means,      // (NUM_MIX, DD)
    const float* __restrict__ scale_tril, // (NUM_MIX, DD, DD)
    const float* __restrict__ mixw,       // (NUM_MIX,)
    const float* __restrict__ seeds,      // (4, HIDDEN, DD)
    const int*   __restrict__ cur_seeds,  // (B,)
    float*       __restrict__ out)        // (B, SEQ, KOUT)
{
    __shared__ __align__(16) float IxB[2][TTILE][HIDDEN];   // 64KB scaled alpha*I*x
    __shared__ __align__(16) float xsB[2][TTILE*INPUT];     // 1KB raw x tiles
    __shared__ __align__(16) float IvL[HIDDEN][INPUT];      // 16KB scaled alpha*I
    __shared__ float PM0[HIDDEN], PM1[HIDDEN], N0[HIDDEN], N1[HIDDEN]; // 8KB
    __shared__ __align__(8) float vring[2][TTILE][2];       // (v0,v1) per step
    __shared__ double Leff[DD*DD];
    __shared__ double meansw[DD];

    const int tid  = threadIdx.x;
    const int lane = tid & 63;
    const int wid  = tid >> 6;
    const int b    = blockIdx.x;
    const int s    = cur_seeds[b];
    const float* xb = x + (size_t)b * SEQ * INPUT;
    float* outb = out + (size_t)b * SEQ * KOUT;

    // ---- mixture weights ----
    double w0 = fmax((double)mixw[0], 1e-6);
    double w1 = fmax((double)mixw[1], 1e-6);
    double wsum = w0 + w1; w0 /= wsum; w1 /= wsum;

    // ---- weighted clamped-tril L, weighted means ----
    if (tid < DD*DD) {
        int d = tid / DD, e = tid % DD;
        double acc = 0.0;
        #pragma unroll
        for (int i = 0; i < NUM_MIX; ++i) {
            float v = scale_tril[i*DD*DD + d*DD + e];
            float c = (d > e) ? v : (d == e ? fabsf(v - 1e-12f) + 1e-12f : 0.0f);
            acc += (i == 0 ? w0 : w1) * (double)c;
        }
        Leff[tid] = acc;
    }
    if (tid < DD)
        meansw[tid] = w0 * (double)means[tid] + w1 * (double)means[DD + tid];
    if (tid < 2*TTILE*INPUT)
        ((float*)xsB)[tid] = xb[tid];          // stage x tiles 0,1
    __syncthreads();

    // ---- per-h params (double), stored pre-scaled ----
    #pragma unroll
    for (int rr = 0; rr < 2; ++rr) {
        int h = tid + rr*256;
        const float* sh = &seeds[(s*HIDDEN + h)*DD];
        double comb[DD];
        #pragma unroll
        for (int d = 0; d < DD; ++d) {
            double acc = meansw[d];
            for (int e = 0; e <= d; ++e)
                acc += Leff[d*DD + e] * (double)sh[e];
            comb[d] = acc;
        }
        PM0[h] = (float)(SCALE_F * (double)AB_F * comb[0]);
        PM1[h] = (float)(SCALE_F * (double)AB_F * comb[1]);
        N0[h]  = (float)comb[2];
        N1[h]  = (float)comb[3];
        #pragma unroll
        for (int i = 0; i < INPUT; ++i)
            IvL[h][i] = (float)(SCALE_F * 0.1 * comb[4 + i]);
    }
    __syncthreads();

    // ---- persistent per-role state ----
    v2f AM0[4], AM1[4], H[4];
    float NM20[8], NM21[8];      // -2 * n per owned unit
    float sn0 = 0.0f, sn1 = 0.0f; // per-lane sum of n
    f4v IvA[3], IvC[3];
    float zf = 0.0f, wst = 0.0f;
    const int pid = (wid - 1)*64 + lane;   // producer id 0..191
    const int zi  = lane - 56;

    if (wid == 0) {
        // consumer owns h = lane + 64*j, paired (2q, 2q+1)
        #pragma unroll
        for (int q = 0; q < 4; ++q) {
            int ha = lane + 64*(2*q), hb = lane + 64*(2*q + 1);
            AM0[q] = (v2f){PM0[ha], PM0[hb]};
            AM1[q] = (v2f){PM1[ha], PM1[hb]};
            H[q]   = (v2f){0.0f, 0.0f};
        }
        #pragma unroll
        for (int j = 0; j < 8; ++j) {
            int h = lane + 64*j;
            float n0 = N0[h], n1 = N1[h];
            NM20[j] = -2.0f * n0;  sn0 += n0;
            NM21[j] = -2.0f * n1;  sn1 += n1;
        }
    } else {
        #pragma unroll
        for (int q = 0; q < 3; ++q) {
            int h = pid + 192*q;
            if (h < HIDDEN) {
                IvA[q] = *(const f4v*)&IvL[h][0];
                IvC[q] = *(const f4v*)&IvL[h][4];
            }
        }
    }

    // producer: fill IxB tile tg; wave1 lanes 56-63 emit the z-filter outputs
    auto produce = [&](int tg) {
        const int pb = tg & 1;
        const float* xs = xsB[pb];
        for (int tt = 0; tt < TTILE; ++tt) {
            f4v xa = *(const f4v*)&xs[tt*INPUT];
            f4v xc = *(const f4v*)&xs[tt*INPUT + 4];
            #pragma unroll
            for (int q = 0; q < 3; ++q) {
                int h = pid + 192*q;
                if (h < HIDDEN) {
                    float v =      IvA[q].x * xa.x;
                    v = fmaf(IvA[q].y, xa.y, v);
                    v = fmaf(IvA[q].z, xa.z, v);
                    v = fmaf(IvA[q].w, xa.w, v);
                    v = fmaf(IvC[q].x, xc.x, v);
                    v = fmaf(IvC[q].y, xc.y, v);
                    v = fmaf(IvC[q].z, xc.z, v);
                    v = fmaf(IvC[q].w, xc.w, v);
                    IxB[pb][tt][h] = v;
                }
            }
        }
        if (wid == 1 && lane >= 56) {
            #pragma unroll 4
            for (int tt = 0; tt < TTILE; ++tt) {
                zf = fmaf(0.9f, zf, 0.1f * xs[tt*INPUT + zi]);
                outb[(tg*TTILE + tt)*KOUT + 2 + zi] = zf;
            }
        }
    };

    // w-EMA for columns 0,1 of a finished tile (lanes 54,55 of wave 1)
    auto process_w = [&](int tile) {
        if (lane == 54 || lane == 55) {
            const int widx = lane & 1;
            for (int tt = 0; tt < TTILE; ++tt) {
                wst = fmaf(0.9f, wst, AB_F * vring[tile & 1][tt][widx]);
                outb[(tile*TTILE + tt)*KOUT + widx] = wst;
            }
        }
    };

    if (wid != 0) produce(0);
    __syncthreads();

    for (int T = 0; T < NTILES; ++T) {
        if (wid == 0) {
            const int pb = T & 1;
            float cc[8], cn[8];
            #pragma unroll
            for (int j = 0; j < 8; ++j) cc[j] = IxB[pb][0][lane + 64*j];
            #pragma unroll
            for (int tt = 0; tt < TTILE; ++tt) {
                if (tt < TTILE-1) {            // prefetch next step (conflict-free)
                    #pragma unroll
                    for (int j = 0; j < 8; ++j)
                        cn[j] = IxB[pb][tt+1][lane + 64*j];
                }
                // ---- tanh dot via exp2 + Montgomery batch inversion ----
                // clamp from above only: exp2(-inf)->0 is exact; cap avoids
                // fp32 overflow in quad products (E <= 2^25, P4 <= 2^100)
                const v2f cap = {25.0f, 25.0f};
                v2f Hm0 = __builtin_elementwise_min(H[0], cap);
                v2f Hm1 = __builtin_elementwise_min(H[1], cap);
                v2f Hm2 = __builtin_elementwise_min(H[2], cap);
                v2f Hm3 = __builtin_elementwise_min(H[3], cap);
                float A0 = __builtin_amdgcn_exp2f(Hm0.x) + 1.0f;
                float A1 = __builtin_amdgcn_exp2f(Hm0.y) + 1.0f;
                float A2 = __builtin_amdgcn_exp2f(Hm1.x) + 1.0f;
                float A3 = __builtin_amdgcn_exp2f(Hm1.y) + 1.0f;
                float A4 = __builtin_amdgcn_exp2f(Hm2.x) + 1.0f;
                float A5 = __builtin_amdgcn_exp2f(Hm2.y) + 1.0f;
                float A6 = __builtin_amdgcn_exp2f(Hm3.x) + 1.0f;
                float A7 = __builtin_amdgcn_exp2f(Hm3.y) + 1.0f;
                // quad 0: r_i = 1/A_i via one rcp
                float r0, r1, r2, r3, r4, r5, r6, r7;
                {
                    float P2 = A0*A1, P3 = P2*A2, P4 = P3*A3;
                    float q4 = __builtin_amdgcn_rcpf(P4);
                    r3 = q4*P3; float q3 = q4*A3;
                    r2 = q3*P2; float q2 = q3*A2;
                    r1 = q2*A0; r0 = q2*A1;
                }
                {
                    float P2 = A4*A5, P3 = P2*A6, P4 = P3*A7;
                    float q4 = __builtin_amdgcn_rcpf(P4);
                    r7 = q4*P3; float q3 = q4*A7;
                    r6 = q3*P2; float q2 = q3*A6;
                    r5 = q2*A4; r4 = q2*A5;
                }
                // p = sum(n) + sum(-2n * r)   == sum(n * tanh)
                float p0 = sn0, p1 = sn1;
                p0 = fmaf(NM20[0], r0, p0);  p1 = fmaf(NM21[0], r0, p1);
                p0 = fmaf(NM20[1], r1, p0);  p1 = fmaf(NM21[1], r1, p1);
                p0 = fmaf(NM20[2], r2, p0);  p1 = fmaf(NM21[2], r2, p1);
                p0 = fmaf(NM20[3], r3, p0);  p1 = fmaf(NM21[3], r3, p1);
                p0 = fmaf(NM20[4], r4, p0);  p1 = fmaf(NM21[4], r4, p1);
                p0 = fmaf(NM20[5], r5, p0);  p1 = fmaf(NM21[5], r5, p1);
                p0 = fmaf(NM20[6], r6, p0);  p1 = fmaf(NM21[6], r6, p1);
                p0 = fmaf(NM20[7], r7, p0);  p1 = fmaf(NM21[7], r7, p1);

                float v0 = wave_allsum(p0);
                float v1 = wave_allsum(p1);

                const v2f nine = {0.9f, 0.9f};
                v2f hc0 = pk_fma(nine, H[0], (v2f){cc[0], cc[1]});
                v2f hc1 = pk_fma(nine, H[1], (v2f){cc[2], cc[3]});
                v2f hc2 = pk_fma(nine, H[2], (v2f){cc[4], cc[5]});
                v2f hc3 = pk_fma(nine, H[3], (v2f){cc[6], cc[7]});

                v2f v0v = {v0, v0}, v1v = {v1, v1};
                H[0] = pk_fma(AM0[0], v0v, pk_fma(AM1[0], v1v, hc0));
                H[1] = pk_fma(AM0[1], v0v, pk_fma(AM1[1], v1v, hc1));
                H[2] = pk_fma(AM0[2], v0v, pk_fma(AM1[2], v1v, hc2));
                H[3] = pk_fma(AM0[3], v0v, pk_fma(AM1[3], v1v, hc3));

                if (lane == 0)
                    *(v2f*)&vring[pb][tt][0] = (v2f){v0, v1};

                #pragma unroll
                for (int j = 0; j < 8; ++j) cc[j] = cn[j];
            }
        } else {
            if (T + 1 < NTILES) produce(T + 1);
            if (wid == 2 && T + 2 < NTILES) {
                const int base = (T + 2)*(TTILE*INPUT);
                xsB[T & 1][lane]      = xb[base + lane];
                xsB[T & 1][lane + 64] = xb[base + lane + 64];
            }
            if (wid == 1 && T >= 1) process_w(T - 1);
        }
        __syncthreads();
    }
    if (wid == 1) process_w(NTILES - 1);
}

extern "C" void kernel_launch(void* const* d_in, const int* in_sizes, int n_in,
                              void* d_out, int out_size, void* d_ws, size_t ws_size,
                              hipStream_t stream) {
    (void)d_ws; (void)ws_size;
    const float* x          = (const float*)d_in[0];
    const float* means      = (const float*)d_in[1];
    const float* scale_tril = (const float*)d_in[2];
    const float* mixw       = (const float*)d_in[3];
    const float* seeds      = (const float*)d_in[4];
    const int*   cur_seeds  = (const int*)d_in[5];
    float* out = (float*)d_out;

    fsm_rnn_kernel<<<BATCH, 256, 0, stream>>>(
        x, means, scale_tril, mixw, seeds, cur_seeds, out);
}